// Round 1
// baseline (1122.017 us; speedup 1.0000x reference)
//
#include <hip/hip_runtime.h>

#define Bsz  256
#define Tlen 2048
#define Hdim 128

typedef __fp16 hf2 __attribute__((ext_vector_type(2)));
typedef __fp16 hf8 __attribute__((ext_vector_type(8)));
typedef float  f32x4 __attribute__((ext_vector_type(4)));
typedef unsigned int ui4 __attribute__((ext_vector_type(4)));

// Raw-HW transcendentals (VOP1, ~1 ulp). R12-verified win.
__device__ __forceinline__ float fexp2_(float x) {
    float r; asm("v_exp_f32 %0, %1" : "=v"(r) : "v"(x)); return r;
}
__device__ __forceinline__ float frcp_(float x) {
    float r; asm("v_rcp_f32 %0, %1" : "=v"(r) : "v"(x)); return r;
}

// pack 8 consecutive f32 into a v8f16 MFMA fragment slice
__device__ __forceinline__ hf8 pack8(const float* p) {
    union { hf2 h2[4]; hf8 h8; } u;
    u.h2[0] = __builtin_amdgcn_cvt_pkrtz(p[0], p[1]);
    u.h2[1] = __builtin_amdgcn_cvt_pkrtz(p[2], p[3]);
    u.h2[2] = __builtin_amdgcn_cvt_pkrtz(p[4], p[5]);
    u.h2[3] = __builtin_amdgcn_cvt_pkrtz(p[6], p[7]);
    return u.h8;
}

#define MFMA(D, A, B) D = __builtin_amdgcn_mfma_f32_16x16x32_f16(A, B, D, 0, 0, 0)

// acc += lo16(a)*lo16(b); acc += hi16(a)*hi16(b)  -- f16 mul, fused f32 accum
// (v_fma_mix_f32: op_sel_hi marks srcs 0,1 as f16; op_sel picks lo/hi half)
#define DOT2W(acc, aw, bw)                                                   \
    do {                                                                     \
        asm("v_fma_mix_f32 %0, %1, %2, %0 op_sel_hi:[1,1,0]"                 \
            : "+v"(acc) : "v"(aw), "v"(bw));                                 \
        asm("v_fma_mix_f32 %0, %1, %2, %0 op_sel:[1,1,0] op_sel_hi:[1,1,0]"  \
            : "+v"(acc) : "v"(aw), "v"(bw));                                 \
    } while (0)

struct Smem {
    float  x[Tlen];       // staged input row
    float  xh[Tlen];      // staged xh outputs
    __fp16 h[2][Hdim];    // double-buffered hidden state (f16)
};

union AV { float4 f4; hf8 h8; ui4 u4; };
union BV { hf8 h8; ui4 u4; };

// grid = 256 blocks (1 batch row each), block = 512 threads (8 waves).
// R24: fc-dot moved off the MFMA pipe.
//  - R21 champion did 16 MFMA/wave/step; 4 of them (D3 = Wfc in all 16
//    columns) existed only to broadcast the scalar xp. Counter math: 2
//    waves/SIMD x 16 MFMA x ~19.4cyc = 621 of the 1085 cyc/step (MfmaUtil
//    49% over whole step => MFMA phase saturated). Those 4 MFMAs are now
//    32 v_fma_mix_f32 (exact f32 accumulation of the SAME f16 products --
//    A regs already hold h, Bf regs already hold Wfc in matching k-layout)
//    + 2 shfl_xor butterflies (q-groups xor16/xor32 -> xp on all 64 lanes,
//    unpredicated gate math preserved). Dot latency hides under the
//    12-MFMA phase; cur is ready BEFORE the gate MFMAs complete.
//  - Gate biases seeded into MFMA C-operands (D0:=bb_r, D1:=bb_z,
//    D2:=bh_n): kills 12 acc zero-inits/step + 2 dependent adds in tail.
//  - log2e constants pre-folded into exp2 args; hn folded to
//    fma(-2w, np, fma(z,h,w)) -- shortens the post-MFMA serial chain.
//  - Everything else is the R21 champion structure: uniform-A broadcast,
//    weights MFMA-only (AGPR-native), one barrier/step, LDS-staged
//    outputs, 8 waves / 2 per SIMD (R16/R22/R23 perturbations regressed).
// Layouts (R18-R21 HW-verified): B: lane l reg j = W[tile*16+(l&15)]
// [c*32+(l>>4)*8+j]; D: col = lane&15, reg 0 valid on all lanes (uniform A).
__global__ __launch_bounds__(512, 2)
void rnn_imp_kernel(const float* __restrict__ x,     // [B, T] (I=1)
                    const float* __restrict__ Wih,   // [384]
                    const float* __restrict__ Whh,   // [384, 128] gate-major (r,z,n)
                    const float* __restrict__ bih,   // [384]
                    const float* __restrict__ bhh,   // [384]
                    const float* __restrict__ Wfc,   // [128]
                    const float* __restrict__ bfc,   // [1]
                    float* __restrict__ out_newin,   // [T, B]
                    float* __restrict__ out_pred)    // [B, T-1]
{
    __shared__ __align__(128) Smem sm;

    const int tid  = threadIdx.x;
    const int b    = blockIdx.x;
    const int wave = tid >> 6;
    const int lane = tid & 63;
    const int m    = lane & 15;      // B/D column = unit-in-tile
    const int q    = lane >> 4;      // k-subchunk

    // stage x row (coalesced); zero h buffer 0
    for (int i = tid; i < Tlen; i += 512) sm.x[i] = x[b * Tlen + i];
    if (tid < Hdim) sm.h[0][tid] = (__fp16)0.0f;

    // ---- B fragments: W^T tiles (consumed only by MFMA -> AGPR-native) ----
    const int r0 = wave * 16 + m;            // unit row, gate r
    const int r1 = r0 + 128;                 // gate z
    const int r2 = r0 + 256;                 // gate n
    const int ko = q * 8;
    hf8 Br0, Br1, Br2, Br3, Bz0, Bz1, Bz2, Bz3, Bn0, Bn1, Bn2, Bn3;
    Br0 = pack8(Whh + r0 * Hdim + 0  + ko);  Br1 = pack8(Whh + r0 * Hdim + 32 + ko);
    Br2 = pack8(Whh + r0 * Hdim + 64 + ko);  Br3 = pack8(Whh + r0 * Hdim + 96 + ko);
    Bz0 = pack8(Whh + r1 * Hdim + 0  + ko);  Bz1 = pack8(Whh + r1 * Hdim + 32 + ko);
    Bz2 = pack8(Whh + r1 * Hdim + 64 + ko);  Bz3 = pack8(Whh + r1 * Hdim + 96 + ko);
    Bn0 = pack8(Whh + r2 * Hdim + 0  + ko);  Bn1 = pack8(Whh + r2 * Hdim + 32 + ko);
    Bn2 = pack8(Whh + r2 * Hdim + 64 + ko);  Bn3 = pack8(Whh + r2 * Hdim + 96 + ko);
    // Wfc for the VALU dot, same k-layout as A fragments: Uf_c[j] = Wfc[c*32+q*8+j]
    BV Uf0, Uf1, Uf2, Uf3;
    Uf0.h8 = pack8(Wfc + 0  + ko);  Uf1.h8 = pack8(Wfc + 32 + ko);
    Uf2.h8 = pack8(Wfc + 64 + ko);  Uf3.h8 = pack8(Wfc + 96 + ko);

    // gate constants for this lane's column unit (valid on all lanes)
    const int ug = wave * 16 + m;
    const float wih_r = Wih[ug], wih_z = Wih[ug + 128], wih_n = Wih[ug + 256];
    const float bb_r = bih[ug]       + bhh[ug];
    const float bb_z = bih[ug + 128] + bhh[ug + 128];
    const float bi_n = bih[ug + 256];
    const float bh_n = bhh[ug + 256];
    const float bfc0 = bfc[0];

    // pre-scaled constants: fold log2e factors out of the per-step chain
    const float kNL2E = -1.44269504f;            // -log2(e)
    const float wr_s  = kNL2E * wih_r;
    const float wz_s  = kNL2E * wih_z;
    const float wn_s  = 2.88539008f * wih_n;     // 2*log2(e)*wih_n
    const float bn_s  = 2.88539008f * bi_n;
    // bias-seeded MFMA C operands (reg 0 is the one consumed)
    const f32x4 C_R = {bb_r, bb_r, bb_r, bb_r};
    const f32x4 C_Z = {bb_z, bb_z, bb_z, bb_z};
    const f32x4 C_N = {bh_n, bh_n, bh_n, bh_n};
    // dot seed: bfc0 contributed exactly once across the q-butterfly
    const float dseed = (q == 0) ? bfc0 : 0.0f;

    float h_old = 0.0f;                      // per-lane copy of unit ug's state

    __syncthreads();

#pragma unroll 1
    for (int t = 0; t < Tlen; ++t) {
        // A fragments: every row = h (uniform-address broadcast reads)
        const float4* hp = (const float4*)sm.h[t & 1];
        AV A0v, A1v, A2v, A3v;
        A0v.f4 = hp[0 * 4 + q];
        A1v.f4 = hp[1 * 4 + q];
        A2v.f4 = hp[2 * 4 + q];
        A3v.f4 = hp[3 * 4 + q];

        // xt early: LDS latency hides under the MFMA block
        float xt = sm.x[t];

        // 12 gate MFMAs (fc tiles removed), bias pre-seeded via C operand
        f32x4 D0 = __builtin_amdgcn_mfma_f32_16x16x32_f16(A0v.h8, Br0, C_R, 0, 0, 0);
        f32x4 D1 = __builtin_amdgcn_mfma_f32_16x16x32_f16(A0v.h8, Bz0, C_Z, 0, 0, 0);
        f32x4 D2 = __builtin_amdgcn_mfma_f32_16x16x32_f16(A0v.h8, Bn0, C_N, 0, 0, 0);
        MFMA(D0, A1v.h8, Br1); MFMA(D1, A1v.h8, Bz1); MFMA(D2, A1v.h8, Bn1);
        MFMA(D0, A2v.h8, Br2); MFMA(D1, A2v.h8, Bz2); MFMA(D2, A2v.h8, Bn2);
        MFMA(D0, A3v.h8, Br3); MFMA(D1, A3v.h8, Bz3); MFMA(D2, A3v.h8, Bn3);

        // xp = Wfc . h on the VALU (hides under MFMA pipe occupancy).
        // Two parallel 16-deep fma_mix chains, then q-group butterfly.
        float a0 = dseed, a1 = 0.0f;
        DOT2W(a0, A0v.u4.x, Uf0.u4.x); DOT2W(a0, A0v.u4.y, Uf0.u4.y);
        DOT2W(a0, A0v.u4.z, Uf0.u4.z); DOT2W(a0, A0v.u4.w, Uf0.u4.w);
        DOT2W(a0, A1v.u4.x, Uf1.u4.x); DOT2W(a0, A1v.u4.y, Uf1.u4.y);
        DOT2W(a0, A1v.u4.z, Uf1.u4.z); DOT2W(a0, A1v.u4.w, Uf1.u4.w);
        DOT2W(a1, A2v.u4.x, Uf2.u4.x); DOT2W(a1, A2v.u4.y, Uf2.u4.y);
        DOT2W(a1, A2v.u4.z, Uf2.u4.z); DOT2W(a1, A2v.u4.w, Uf2.u4.w);
        DOT2W(a1, A3v.u4.x, Uf3.u4.x); DOT2W(a1, A3v.u4.y, Uf3.u4.y);
        DOT2W(a1, A3v.u4.z, Uf3.u4.z); DOT2W(a1, A3v.u4.w, Uf3.u4.w);
        float xp = a0 + a1;
        xp += __shfl_xor(xp, 16, 64);    // combine q0<->q1, q2<->q3
        xp += __shfl_xor(xp, 32, 64);    // combine (q01)<->(q23): all lanes have xp
        float xh  = xp;                  // bfc0 already seeded
        float cur = ((xt == 128.0f) && (t != 0)) ? xh : xt;

        // pre-computable gate addends (ready before MFMAs retire)
        float pr = wr_s * cur;
        float pz = wz_s * cur;
        float an = fmaf(wn_s, cur, bn_s);

        // gates: unpredicated on all 64 lanes (q-copies compute identical hn)
        float r  = frcp_(1.0f + fexp2_(fmaf(kNL2E, D0[0], pr)));
        float z  = frcp_(1.0f + fexp2_(fmaf(kNL2E, D1[0], pz)));
        float tn = 2.88539008f * D2[0];          // D2 already includes bh_n
        float np = frcp_(fexp2_(fmaf(r, tn, an)) + 1.0f);   // n = 1 - 2*np
        float w  = 1.0f - z;
        float hz = fmaf(z, h_old, w);
        float hn = fmaf(-2.0f * w, np, hz);      // (1-z)*n + z*h
        h_old = hn;

        if (lane < 16) sm.h[(t + 1) & 1][ug] = (__fp16)hn;
        if (tid == 0)  sm.xh[t] = xh;
        __syncthreads();
    }

    // bulk flush; cur reconstructed from pristine x + xh
    for (int i = tid; i < Tlen; i += 512) {
        float xv = sm.x[i];
        float cv = ((xv == 128.0f) && (i != 0)) ? sm.xh[i] : xv;
        out_newin[i * Bsz + b] = cv;
    }
    for (int i = tid; i < Tlen - 1; i += 512)
        out_pred[b * (Tlen - 1) + i] = sm.xh[i + 1];
}

extern "C" void kernel_launch(void* const* d_in, const int* in_sizes, int n_in,
                              void* d_out, int out_size, void* d_ws, size_t ws_size,
                              hipStream_t stream) {
    const float* x   = (const float*)d_in[0];
    const float* Wih = (const float*)d_in[1];
    const float* Whh = (const float*)d_in[2];
    const float* bih = (const float*)d_in[3];
    const float* bhh = (const float*)d_in[4];
    const float* Wfc = (const float*)d_in[5];
    const float* bfc = (const float*)d_in[6];

    float* out_newin = (float*)d_out;                 // [T*B] = 524288
    float* out_pred  = out_newin + Tlen * Bsz;        // [B*(T-1)] = 524032

    rnn_imp_kernel<<<Bsz, 512, 0, stream>>>(x, Wih, Whh, bih, bhh, Wfc, bfc,
                                            out_newin, out_pred);
}

// Round 2
// 920.010 us; speedup vs baseline: 1.2196x; 1.2196x over previous
//
#include <hip/hip_runtime.h>

#define Bsz  256
#define Tlen 2048
#define Hdim 128

typedef __fp16 hf2 __attribute__((ext_vector_type(2)));
typedef __fp16 hf8 __attribute__((ext_vector_type(8)));
typedef float  f32x4 __attribute__((ext_vector_type(4)));

// Raw-HW transcendentals (VOP1, ~1 ulp). R12-verified win.
__device__ __forceinline__ float fexp2_(float x) {
    float r; asm("v_exp_f32 %0, %1" : "=v"(r) : "v"(x)); return r;
}
__device__ __forceinline__ float frcp_(float x) {
    float r; asm("v_rcp_f32 %0, %1" : "=v"(r) : "v"(x)); return r;
}

// pack 8 consecutive f32 into a v8f16 MFMA fragment slice
__device__ __forceinline__ hf8 pack8(const float* p) {
    union { hf2 h2[4]; hf8 h8; } u;
    u.h2[0] = __builtin_amdgcn_cvt_pkrtz(p[0], p[1]);
    u.h2[1] = __builtin_amdgcn_cvt_pkrtz(p[2], p[3]);
    u.h2[2] = __builtin_amdgcn_cvt_pkrtz(p[4], p[5]);
    u.h2[3] = __builtin_amdgcn_cvt_pkrtz(p[6], p[7]);
    return u.h8;
}
__device__ __forceinline__ hf8 bch8(float4 v) { return __builtin_bit_cast(hf8, v); }

#define MFMA(D, A, B) D = __builtin_amdgcn_mfma_f32_16x16x32_f16(A, B, D, 0, 0, 0)

struct Smem {
    float  x[Tlen];       // staged input row
    float  xh[Tlen];      // staged xh outputs
    __fp16 h[2][Hdim];    // double-buffered hidden state (f16)
};

// grid = 256 blocks (1 batch row each), block = 512 threads (8 waves).
// R25 = R21 champion structure (16 MFMA/wave/step: fc stays on the MFMA
// pipe) + the R24-verified tail optimizations. R24 post-mortem: the kernel
// is critical-path-latency-bound, NOT MFMA-issue-bound — moving fc to the
// VALU shrank MfmaUtil 49->29% exactly as predicted but lengthened the
// serial chain (16-deep fma_mix + 2 LDS shuffles) and regressed 21%.
// Changes vs R21 (all numerics verified correct in R24, absmax identical):
//  - Bias-seeded MFMA C operands: D0:=bb_r, D1:=bb_z, D2:=bh_n, D3:=bfc0.
//    Kills 16 acc zero-inits + 3 dependent adds per step.
//  - Chain reorder: D3 (fc) + D0 (r-gate) chains complete in the FIRST 8
//    MFMAs; D1/D2 in the last 8. cur + the whole r-sigmoid now hide under
//    D1/D2 issue (~310 cyc); serial tail after last MFMA shrinks to
//    D2 -> fma -> exp -> add -> rcp -> 2 fma -> cvt -> write (~70 cyc).
//  - log2e pre-folded into exp2 args; hn = fma(-2w, np, fma(z,h,w)).
//  - Everything else: uniform-A broadcast, weights MFMA-only (AGPR-
//    native), one barrier/step, LDS-staged outputs, 8 waves / 2 per SIMD
//    (R16: 16 waves +37%; R22: 4 waves +16%; R23 split-acc +7%).
// Layouts (R18-R21 HW-verified): B: lane l reg j = W[tile*16+(l&15)]
// [c*32+(l>>4)*8+j]; D: col = lane&15, reg 0 valid on all lanes (uniform A).
__global__ __launch_bounds__(512, 2)
void rnn_imp_kernel(const float* __restrict__ x,     // [B, T] (I=1)
                    const float* __restrict__ Wih,   // [384]
                    const float* __restrict__ Whh,   // [384, 128] gate-major (r,z,n)
                    const float* __restrict__ bih,   // [384]
                    const float* __restrict__ bhh,   // [384]
                    const float* __restrict__ Wfc,   // [128]
                    const float* __restrict__ bfc,   // [1]
                    float* __restrict__ out_newin,   // [T, B]
                    float* __restrict__ out_pred)    // [B, T-1]
{
    __shared__ __align__(128) Smem sm;

    const int tid  = threadIdx.x;
    const int b    = blockIdx.x;
    const int wave = tid >> 6;
    const int lane = tid & 63;
    const int m    = lane & 15;      // B/D column = unit-in-tile
    const int q    = lane >> 4;      // k-subchunk

    // stage x row (coalesced); zero h buffer 0
    for (int i = tid; i < Tlen; i += 512) sm.x[i] = x[b * Tlen + i];
    if (tid < Hdim) sm.h[0][tid] = (__fp16)0.0f;

    // ---- B fragments: W^T tiles (consumed only by MFMA -> AGPR-native) ----
    const int r0 = wave * 16 + m;            // unit row, gate r
    const int r1 = r0 + 128;                 // gate z
    const int r2 = r0 + 256;                 // gate n
    const int ko = q * 8;
    hf8 Br0, Br1, Br2, Br3, Bz0, Bz1, Bz2, Bz3,
        Bn0, Bn1, Bn2, Bn3, Bf0, Bf1, Bf2, Bf3;
    Br0 = pack8(Whh + r0 * Hdim + 0  + ko);  Br1 = pack8(Whh + r0 * Hdim + 32 + ko);
    Br2 = pack8(Whh + r0 * Hdim + 64 + ko);  Br3 = pack8(Whh + r0 * Hdim + 96 + ko);
    Bz0 = pack8(Whh + r1 * Hdim + 0  + ko);  Bz1 = pack8(Whh + r1 * Hdim + 32 + ko);
    Bz2 = pack8(Whh + r1 * Hdim + 64 + ko);  Bz3 = pack8(Whh + r1 * Hdim + 96 + ko);
    Bn0 = pack8(Whh + r2 * Hdim + 0  + ko);  Bn1 = pack8(Whh + r2 * Hdim + 32 + ko);
    Bn2 = pack8(Whh + r2 * Hdim + 64 + ko);  Bn3 = pack8(Whh + r2 * Hdim + 96 + ko);
    // Wfc in ALL columns: every lane's D3 reg 0 = xp
    Bf0 = pack8(Wfc + 0  + ko);  Bf1 = pack8(Wfc + 32 + ko);
    Bf2 = pack8(Wfc + 64 + ko);  Bf3 = pack8(Wfc + 96 + ko);

    // gate constants for this lane's column unit (valid on all lanes)
    const int ug = wave * 16 + m;
    const float wih_r = Wih[ug], wih_z = Wih[ug + 128], wih_n = Wih[ug + 256];
    const float bb_r = bih[ug]       + bhh[ug];
    const float bb_z = bih[ug + 128] + bhh[ug + 128];
    const float bi_n = bih[ug + 256];
    const float bh_n = bhh[ug + 256];
    const float bfc0 = bfc[0];

    // pre-scaled constants: fold log2e factors out of the per-step chain
    const float kNL2E = -1.44269504f;            // -log2(e)
    const float wr_s  = kNL2E * wih_r;
    const float wz_s  = kNL2E * wih_z;
    const float wn_s  = 2.88539008f * wih_n;     // 2*log2(e)*wih_n
    const float bn_s  = 2.88539008f * bi_n;
    // bias-seeded MFMA C operands (reg 0 is the one consumed)
    const f32x4 C_R = {bb_r, bb_r, bb_r, bb_r};
    const f32x4 C_Z = {bb_z, bb_z, bb_z, bb_z};
    const f32x4 C_N = {bh_n, bh_n, bh_n, bh_n};
    const f32x4 C_F = {bfc0, bfc0, bfc0, bfc0};

    float h_old = 0.0f;                      // per-lane copy of unit ug's state

    __syncthreads();

#pragma unroll 1
    for (int t = 0; t < Tlen; ++t) {
        // A fragments: every row = h (uniform-address broadcast reads)
        const float4* hp = (const float4*)sm.h[t & 1];
        hf8 A0 = bch8(hp[0 * 4 + q]);
        hf8 A1 = bch8(hp[1 * 4 + q]);
        hf8 A2 = bch8(hp[2 * 4 + q]);
        hf8 A3 = bch8(hp[3 * 4 + q]);

        // xt early: LDS latency hides under the MFMA block
        float xt = sm.x[t];

        // ---- phase 1: D3 (fc) and D0 (r-gate) chains complete first ----
        f32x4 D3 = __builtin_amdgcn_mfma_f32_16x16x32_f16(A0, Bf0, C_F, 0, 0, 0);
        f32x4 D0 = __builtin_amdgcn_mfma_f32_16x16x32_f16(A0, Br0, C_R, 0, 0, 0);
        MFMA(D3, A1, Bf1); MFMA(D0, A1, Br1);
        MFMA(D3, A2, Bf2); MFMA(D0, A2, Br2);
        MFMA(D3, A3, Bf3); MFMA(D0, A3, Br3);

        // ---- phase 2: D1/D2 chains; cur + r-sigmoid hide under their issue
        f32x4 D1 = __builtin_amdgcn_mfma_f32_16x16x32_f16(A0, Bz0, C_Z, 0, 0, 0);
        f32x4 D2 = __builtin_amdgcn_mfma_f32_16x16x32_f16(A0, Bn0, C_N, 0, 0, 0);

        float xh  = D3[0];                   // bfc0 pre-seeded
        float cur = ((xt == 128.0f) && (t != 0)) ? xh : xt;
        float pr  = wr_s * cur;
        float pz  = wz_s * cur;
        float an  = fmaf(wn_s, cur, bn_s);
        float r   = frcp_(1.0f + fexp2_(fmaf(kNL2E, D0[0], pr)));

        MFMA(D1, A1, Bz1); MFMA(D2, A1, Bn1);
        MFMA(D1, A2, Bz2); MFMA(D2, A2, Bn2);
        MFMA(D1, A3, Bz3); MFMA(D2, A3, Bn3);

        // gates: unpredicated on all 64 lanes (q-copies compute identical hn)
        float z  = frcp_(1.0f + fexp2_(fmaf(kNL2E, D1[0], pz)));
        float tn = 2.88539008f * D2[0];          // D2 already includes bh_n
        float np = frcp_(fexp2_(fmaf(r, tn, an)) + 1.0f);   // n = 1 - 2*np
        float w  = 1.0f - z;
        float hz = fmaf(z, h_old, w);
        float hn = fmaf(-2.0f * w, np, hz);      // (1-z)*n + z*h
        h_old = hn;

        if (lane < 16) sm.h[(t + 1) & 1][ug] = (__fp16)hn;
        if (tid == 0)  sm.xh[t] = xh;
        __syncthreads();
    }

    // bulk flush; cur reconstructed from pristine x + xh
    for (int i = tid; i < Tlen; i += 512) {
        float xv = sm.x[i];
        float cv = ((xv == 128.0f) && (i != 0)) ? sm.xh[i] : xv;
        out_newin[i * Bsz + b] = cv;
    }
    for (int i = tid; i < Tlen - 1; i += 512)
        out_pred[b * (Tlen - 1) + i] = sm.xh[i + 1];
}

extern "C" void kernel_launch(void* const* d_in, const int* in_sizes, int n_in,
                              void* d_out, int out_size, void* d_ws, size_t ws_size,
                              hipStream_t stream) {
    const float* x   = (const float*)d_in[0];
    const float* Wih = (const float*)d_in[1];
    const float* Whh = (const float*)d_in[2];
    const float* bih = (const float*)d_in[3];
    const float* bhh = (const float*)d_in[4];
    const float* Wfc = (const float*)d_in[5];
    const float* bfc = (const float*)d_in[6];

    float* out_newin = (float*)d_out;                 // [T*B] = 524288
    float* out_pred  = out_newin + Tlen * Bsz;        // [B*(T-1)] = 524032

    rnn_imp_kernel<<<Bsz, 512, 0, stream>>>(x, Wih, Whh, bih, bhh, Wfc, bfc,
                                            out_newin, out_pred);
}